// Round 6
// baseline (40.294 us; speedup 1.0000x reference)
//
#include <hip/hip_runtime.h>

// Window_Crop: per-batch sliding-window average pooling over 5 aspect ratios
// (stride 1) + argmax over first 4 ratio groups.
//
// Ratios (exact Python float semantics: 1024 // 25.6 == 39.0):
//   (32,32) N=6561  off 0
//   (25,39) N=6512  off 6561
//   (39,25) N=6512  off 13073
//   (38,26) N=6525  off 19585
//   (26,38) N=6525  off 26110   (excluded from argmax)
//   total 32635
//
// Persistent grid: 512 blocks x 2 images, 51 KB LDS -> 2 blocks/CU.
// BLOCK=768: 2 blocks/CU x 12 waves = 24 waves/CU (round-3 evidence:
// 24 waves/CU -> ~6.9 us/image vs ~9.9 at 16 waves). __launch_bounds__(768,6)
// caps VGPR at 85 so 6 waves/SIMD (both blocks) is guaranteed.
// T14: image B's float4 loads issued before image A's window phase.

#define B_TOTAL 1024
#define GRID    512
#define HW      112
#define NPIX    (HW * HW)
#define NV4     (NPIX / 4)           // 3136 float4 per image
#define PITCH   113
#define TOTAL_W 32635
#define BLOCK   768
#define LDV4    5                    // ceil(3136 / 768)
#define SEG     28                   // 112 / 4 segments per scan line

template<int KH, int KW, int OFF, bool TRACK>
__device__ __forceinline__ void windows_group(const float* __restrict__ S,
                                              float* __restrict__ out_scores,
                                              int tid, float& bestv, int& besti) {
    constexpr int OH  = HW - KH + 1;
    constexpr int OW  = HW - KW + 1;
    constexpr int OWP = (OW + 1) / 2;     // column pairs per row
    constexpr int NP  = OH * OWP;
    constexpr int D   = KH * PITCH;       // bottom-row offset (dwords)
    constexpr float inv = 1.0f / (float)(KH * KW);
    for (int p = tid; p < NP; p += BLOCK) {
        const int i  = p / OWP;           // const divisor -> magic mul
        const int j  = (p - i * OWP) * 2;
        const int A  = i * PITCH + j;
        const int Ab = A + D;
        const float t0  = S[A],       t1  = S[A + 1];
        const float tK0 = S[A + KW],  tK1 = S[A + KW + 1];
        const float b0  = S[Ab],      b1  = S[Ab + 1];
        const float bK0 = S[Ab + KW], bK1 = S[Ab + KW + 1];
        const int w = i * OW + j;
        const float sc0 = (bK0 - tK0 - b0 + t0) * inv;
        out_scores[OFF + w] = sc0;
        if (TRACK && sc0 > bestv) { bestv = sc0; besti = OFF + w; }
        if ((OW & 1) == 0 || j + 1 < OW) {
            const float sc1 = (bK1 - tK1 - b1 + t1) * inv;
            out_scores[OFF + w + 1] = sc1;
            if (TRACK && sc1 > bestv) { bestv = sc1; besti = OFF + w + 1; }
        }
    }
}

__device__ __forceinline__ void scans(float* __restrict__ S, int tid, int bl) {
    // row-wise prefix sums: 112 rows x 4 segments of 28; partials in regs,
    // shfl fixup. 113-stride across threads: gcd(17,32)=1 -> conflict-free.
    if (tid < HW * 4) {
        const int r = tid >> 2, s = tid & 3;
        float* row = &S[(r + 1) * PITCH];
        const int c0 = 1 + s * SEG;
        float pref[SEG];
        float run = 0.0f;
        #pragma unroll
        for (int k = 0; k < SEG; ++k) { run += row[c0 + k]; pref[k] = run; }
        const float v0 = __shfl(run, bl, 64), v1 = __shfl(run, bl + 1, 64),
                    v2 = __shfl(run, bl + 2, 64);
        float off = 0.0f;
        if (s > 0) off += v0;
        if (s > 1) off += v1;
        if (s > 2) off += v2;
        #pragma unroll
        for (int k = 0; k < SEG; ++k) row[c0 + k] = pref[k] + off;
    }
    __syncthreads();
    // column-wise prefix sums, same scheme (consecutive addrs across threads)
    if (tid < HW * 4) {
        const int c = tid >> 2, s = tid & 3;
        float* col = &S[c + 1];
        const int r0 = 1 + s * SEG;
        float pref[SEG];
        float run = 0.0f;
        #pragma unroll
        for (int k = 0; k < SEG; ++k) { run += col[(r0 + k) * PITCH]; pref[k] = run; }
        const float v0 = __shfl(run, bl, 64), v1 = __shfl(run, bl + 1, 64),
                    v2 = __shfl(run, bl + 2, 64);
        float off = 0.0f;
        if (s > 0) off += v0;
        if (s > 1) off += v1;
        if (s > 2) off += v2;
        #pragma unroll
        for (int k = 0; k < SEG; ++k) col[(r0 + k) * PITCH] = pref[k] + off;
    }
    __syncthreads();
}

__device__ __forceinline__ void write_img(float* __restrict__ S, const float4* v,
                                          int tid) {
    #pragma unroll
    for (int k = 0; k < LDV4; ++k) {
        const int i = tid + k * BLOCK;
        if (i < NV4) {
            const int r = i / (HW / 4);
            const int c = (i - r * (HW / 4)) * 4;
            float* dst = &S[(r + 1) * PITCH + (c + 1)];
            dst[0] = v[k].x; dst[1] = v[k].y; dst[2] = v[k].z; dst[3] = v[k].w;
        }
    }
}

__device__ __forceinline__ void windows_phase(const float* __restrict__ S,
                                              float* __restrict__ out, int b,
                                              int tid, int lane,
                                              float* wv, int* wi) {
    float bestv = -3.402823466e+38f;
    int   besti = 0;
    float* out_scores = out + 2 * B_TOTAL + (size_t)b * TOTAL_W;

    windows_group<32, 32,     0, true >(S, out_scores, tid, bestv, besti);
    windows_group<25, 39,  6561, true >(S, out_scores, tid, bestv, besti);
    windows_group<39, 25, 13073, true >(S, out_scores, tid, bestv, besti);
    windows_group<38, 26, 19585, true >(S, out_scores, tid, bestv, besti);
    windows_group<26, 38, 26110, false>(S, out_scores, tid, bestv, besti);

    #pragma unroll
    for (int d = 32; d > 0; d >>= 1) {
        const float ov = __shfl_down(bestv, d, 64);
        const int   oi = __shfl_down(besti, d, 64);
        if (ov > bestv || (ov == bestv && oi < besti)) { bestv = ov; besti = oi; }
    }
    if (lane == 0) { wv[tid >> 6] = bestv; wi[tid >> 6] = besti; }
    __syncthreads();
    if (tid == 0) {
        float bv = wv[0]; int bi = wi[0];
        #pragma unroll
        for (int k = 1; k < BLOCK / 64; ++k) {
            if (wv[k] > bv || (wv[k] == bv && wi[k] < bi)) { bv = wv[k]; bi = wi[k]; }
        }
        out[b]           = (float)bi;    // idx (exact in fp32: < 2^24)
        out[B_TOTAL + b] = bv;           // prop_scores
    }
}

__global__ __launch_bounds__(BLOCK, 6)
void window_crop_kernel(const float* __restrict__ x, float* __restrict__ out) {
    __shared__ float S[PITCH * PITCH];           // 51,076 B integral image
    __shared__ float wv[BLOCK / 64];
    __shared__ int   wi[BLOCK / 64];

    const int tid  = threadIdx.x;
    const int lane = tid & 63;
    const int bl   = lane & ~3;

    const int bA = blockIdx.x;
    const int bB = blockIdx.x + GRID;

    // zero border row/col once; images only touch [1..112]^2
    for (int i = tid; i < PITCH; i += BLOCK) {
        S[i] = 0.0f;
        S[i * PITCH] = 0.0f;
    }

    // ---- image A: load -> LDS -> scans ----
    float4 va[LDV4];
    const float4* imgA = (const float4*)(x + (size_t)bA * NPIX);
    #pragma unroll
    for (int k = 0; k < LDV4; ++k) {
        const int i = tid + k * BLOCK;
        if (i < NV4) va[k] = imgA[i];
    }
    write_img(S, va, tid);
    __syncthreads();
    scans(S, tid, bl);

    // ---- issue image B's loads (consumed after A's window phase) ----
    float4 vb[LDV4];
    const float4* imgB = (const float4*)(x + (size_t)bB * NPIX);
    #pragma unroll
    for (int k = 0; k < LDV4; ++k) {
        const int i = tid + k * BLOCK;
        if (i < NV4) vb[k] = imgB[i];
    }

    // ---- image A: windows + argmax (write-heavy; B loads in flight) ----
    windows_phase(S, out, bA, tid, lane, wv, wi);
    __syncthreads();                 // all window reads of S done

    // ---- image B: LDS -> scans -> windows ----
    write_img(S, vb, tid);
    __syncthreads();
    scans(S, tid, bl);
    windows_phase(S, out, bB, tid, lane, wv, wi);
}

extern "C" void kernel_launch(void* const* d_in, const int* in_sizes, int n_in,
                              void* d_out, int out_size, void* d_ws, size_t ws_size,
                              hipStream_t stream) {
    const float* x = (const float*)d_in[0];
    float* out     = (float*)d_out;
    window_crop_kernel<<<GRID, BLOCK, 0, stream>>>(x, out);
}

// Round 7
// 39.139 us; speedup vs baseline: 1.0295x; 1.0295x over previous
//
#include <hip/hip_runtime.h>

// Window_Crop: per-batch sliding-window average pooling over 5 aspect ratios
// (stride 1) + argmax over first 4 ratio groups.
//
// Ratios (exact Python float semantics: 1024 // 25.6 == 39.0):
//   (32,32) N=6561  off 0
//   (25,39) N=6512  off 6561
//   (39,25) N=6512  off 13073
//   (38,26) N=6525  off 19585
//   (26,38) N=6525  off 26110   (excluded from argmax)
//   total 32635
//
// Persistent grid: 512 blocks x 2 images, 51 KB LDS -> 2 blocks/CU.
// T14: image B's float4 loads issued before image A's window phase.
// Window loop: ONE window per thread, stride-1 lane->index mapping, so every
// wave store is 256 B fully-packed contiguous (the round-3..6 "paired" loop
// emitted stride-2-lane global_store_dword pairs -> half-covered cache lines
// per store instruction; suspected cause of the ~5 TB/s write plateau).

#define B_TOTAL 1024
#define GRID    512
#define HW      112
#define NPIX    (HW * HW)
#define NV4     (NPIX / 4)           // 3136 float4 per image
#define PITCH   113
#define TOTAL_W 32635
#define BLOCK   512
#define LDV4    7                    // ceil(3136 / 512)
#define SEG     28                   // 112 / 4 segments per scan line

template<int KH, int KW, int OFF, bool TRACK>
__device__ __forceinline__ void windows_group(const float* __restrict__ S,
                                              float* __restrict__ out_scores,
                                              int tid, float& bestv, int& besti) {
    constexpr int OH = HW - KH + 1;
    constexpr int OW = HW - KW + 1;
    constexpr int N  = OH * OW;
    constexpr int D  = KH * PITCH;        // bottom-row offset (dwords)
    constexpr float inv = 1.0f / (float)(KH * KW);
    for (int w = tid; w < N; w += BLOCK) {
        const int i  = w / OW;            // const divisor -> magic mul
        const int j  = w - i * OW;
        const int A  = i * PITCH + j;     // top-left corner
        const int Ab = A + D;             // bottom-left corner
        const float s = S[Ab + KW] - S[A + KW] - S[Ab] + S[A];
        const float sc = s * inv;
        out_scores[OFF + w] = sc;         // lanes stride-1: packed 256B/wave
        if (TRACK && sc > bestv) { bestv = sc; besti = OFF + w; }
    }
}

__device__ __forceinline__ void scans(float* __restrict__ S, int tid, int bl) {
    // row-wise prefix sums: 112 rows x 4 segments of 28; partials in regs,
    // shfl fixup. 113-stride across threads: gcd(17,32)=1 -> conflict-free.
    if (tid < HW * 4) {
        const int r = tid >> 2, s = tid & 3;
        float* row = &S[(r + 1) * PITCH];
        const int c0 = 1 + s * SEG;
        float pref[SEG];
        float run = 0.0f;
        #pragma unroll
        for (int k = 0; k < SEG; ++k) { run += row[c0 + k]; pref[k] = run; }
        const float v0 = __shfl(run, bl, 64), v1 = __shfl(run, bl + 1, 64),
                    v2 = __shfl(run, bl + 2, 64);
        float off = 0.0f;
        if (s > 0) off += v0;
        if (s > 1) off += v1;
        if (s > 2) off += v2;
        #pragma unroll
        for (int k = 0; k < SEG; ++k) row[c0 + k] = pref[k] + off;
    }
    __syncthreads();
    // column-wise prefix sums, same scheme (consecutive addrs across threads)
    if (tid < HW * 4) {
        const int c = tid >> 2, s = tid & 3;
        float* col = &S[c + 1];
        const int r0 = 1 + s * SEG;
        float pref[SEG];
        float run = 0.0f;
        #pragma unroll
        for (int k = 0; k < SEG; ++k) { run += col[(r0 + k) * PITCH]; pref[k] = run; }
        const float v0 = __shfl(run, bl, 64), v1 = __shfl(run, bl + 1, 64),
                    v2 = __shfl(run, bl + 2, 64);
        float off = 0.0f;
        if (s > 0) off += v0;
        if (s > 1) off += v1;
        if (s > 2) off += v2;
        #pragma unroll
        for (int k = 0; k < SEG; ++k) col[(r0 + k) * PITCH] = pref[k] + off;
    }
    __syncthreads();
}

__device__ __forceinline__ void write_img(float* __restrict__ S, const float4* v,
                                          int tid) {
    #pragma unroll
    for (int k = 0; k < LDV4; ++k) {
        const int i = tid + k * BLOCK;
        if (i < NV4) {
            const int r = i / (HW / 4);
            const int c = (i - r * (HW / 4)) * 4;
            float* dst = &S[(r + 1) * PITCH + (c + 1)];
            dst[0] = v[k].x; dst[1] = v[k].y; dst[2] = v[k].z; dst[3] = v[k].w;
        }
    }
}

__device__ __forceinline__ void windows_phase(const float* __restrict__ S,
                                              float* __restrict__ out, int b,
                                              int tid, int lane,
                                              float* wv, int* wi) {
    float bestv = -3.402823466e+38f;
    int   besti = 0;
    float* out_scores = out + 2 * B_TOTAL + (size_t)b * TOTAL_W;

    windows_group<32, 32,     0, true >(S, out_scores, tid, bestv, besti);
    windows_group<25, 39,  6561, true >(S, out_scores, tid, bestv, besti);
    windows_group<39, 25, 13073, true >(S, out_scores, tid, bestv, besti);
    windows_group<38, 26, 19585, true >(S, out_scores, tid, bestv, besti);
    windows_group<26, 38, 26110, false>(S, out_scores, tid, bestv, besti);

    #pragma unroll
    for (int d = 32; d > 0; d >>= 1) {
        const float ov = __shfl_down(bestv, d, 64);
        const int   oi = __shfl_down(besti, d, 64);
        if (ov > bestv || (ov == bestv && oi < besti)) { bestv = ov; besti = oi; }
    }
    if (lane == 0) { wv[tid >> 6] = bestv; wi[tid >> 6] = besti; }
    __syncthreads();
    if (tid == 0) {
        float bv = wv[0]; int bi = wi[0];
        #pragma unroll
        for (int k = 1; k < BLOCK / 64; ++k) {
            if (wv[k] > bv || (wv[k] == bv && wi[k] < bi)) { bv = wv[k]; bi = wi[k]; }
        }
        out[b]           = (float)bi;    // idx (exact in fp32: < 2^24)
        out[B_TOTAL + b] = bv;           // prop_scores
    }
}

__global__ __launch_bounds__(BLOCK)
void window_crop_kernel(const float* __restrict__ x, float* __restrict__ out) {
    __shared__ float S[PITCH * PITCH];           // 51,076 B integral image
    __shared__ float wv[BLOCK / 64];
    __shared__ int   wi[BLOCK / 64];

    const int tid  = threadIdx.x;
    const int lane = tid & 63;
    const int bl   = lane & ~3;

    const int bA = blockIdx.x;
    const int bB = blockIdx.x + GRID;

    // zero border row/col once; images only touch [1..112]^2
    for (int i = tid; i < PITCH; i += BLOCK) {
        S[i] = 0.0f;
        S[i * PITCH] = 0.0f;
    }

    // ---- image A: load -> LDS -> scans ----
    float4 va[LDV4];
    const float4* imgA = (const float4*)(x + (size_t)bA * NPIX);
    #pragma unroll
    for (int k = 0; k < LDV4; ++k) {
        const int i = tid + k * BLOCK;
        if (i < NV4) va[k] = imgA[i];
    }
    write_img(S, va, tid);
    __syncthreads();
    scans(S, tid, bl);

    // ---- issue image B's loads (consumed after A's window phase) ----
    float4 vb[LDV4];
    const float4* imgB = (const float4*)(x + (size_t)bB * NPIX);
    #pragma unroll
    for (int k = 0; k < LDV4; ++k) {
        const int i = tid + k * BLOCK;
        if (i < NV4) vb[k] = imgB[i];
    }

    // ---- image A: windows + argmax (write-heavy; B loads in flight) ----
    windows_phase(S, out, bA, tid, lane, wv, wi);
    __syncthreads();                 // all window reads of S done

    // ---- image B: LDS -> scans -> windows ----
    write_img(S, vb, tid);
    __syncthreads();
    scans(S, tid, bl);
    windows_phase(S, out, bB, tid, lane, wv, wi);
}

extern "C" void kernel_launch(void* const* d_in, const int* in_sizes, int n_in,
                              void* d_out, int out_size, void* d_ws, size_t ws_size,
                              hipStream_t stream) {
    const float* x = (const float*)d_in[0];
    float* out     = (float*)d_out;
    window_crop_kernel<<<GRID, BLOCK, 0, stream>>>(x, out);
}